// Round 1
// baseline (638.264 us; speedup 1.0000x reference)
//
#include <hip/hip_runtime.h>
#include <cstdint>

#define B_   2
#define N_   1024
#define DN_  128
#define DE_  16
#define DG_  128
#define MID_ 64
#define OUT_ 128

// ---------------------------------------------------------------------------
// Per-node projections: values = f@Wm+bm, skip = f@Wskip+bskip,
// p1 = f@W1+b1, p2 = f@W2+b2.  8 rows per block to amortize weight reads.
// ---------------------------------------------------------------------------
__global__ void __launch_bounds__(128) proj_rows(
    const float* __restrict__ features,
    const float* __restrict__ Wm, const float* __restrict__ bm,
    const float* __restrict__ Wskip, const float* __restrict__ bskip,
    const float* __restrict__ W1, const float* __restrict__ b1,
    const float* __restrict__ W2, const float* __restrict__ b2,
    float* __restrict__ values, float* __restrict__ skipo,
    float* __restrict__ p1, float* __restrict__ p2)
{
    const int t  = threadIdx.x;         // 0..127
    const int r0 = blockIdx.x * 8;      // first row of this block
    __shared__ float feat[8][DN_];
    #pragma unroll
    for (int q = 0; q < 8; ++q)
        feat[q][t] = features[(size_t)(r0 + q) * DN_ + t];
    __syncthreads();

    float accv[8] = {}, accs[8] = {};
    for (int k = 0; k < DN_; ++k) {
        const float wv = Wm[k * OUT_ + t];
        const float ws = Wskip[k * OUT_ + t];
        #pragma unroll
        for (int q = 0; q < 8; ++q) {
            const float f = feat[q][k];
            accv[q] += f * wv;
            accs[q] += f * ws;
        }
    }
    #pragma unroll
    for (int q = 0; q < 8; ++q) {
        values[(size_t)(r0 + q) * OUT_ + t] = accv[q] + bm[t];
        skipo [(size_t)(r0 + q) * OUT_ + t] = accs[q] + bskip[t];
    }

    if (t < MID_) {
        float a1[8] = {}, a2[8] = {};
        for (int k = 0; k < DN_; ++k) {
            const float w1 = W1[k * MID_ + t];
            const float w2 = W2[k * MID_ + t];
            #pragma unroll
            for (int q = 0; q < 8; ++q) {
                const float f = feat[q][k];
                a1[q] += f * w1;
                a2[q] += f * w2;
            }
        }
        #pragma unroll
        for (int q = 0; q < 8; ++q) {
            p1[(size_t)(r0 + q) * MID_ + t] = a1[q] + b1[t];
            p2[(size_t)(r0 + q) * MID_ + t] = a2[q] + b2[t];
        }
    }
}

// ---------------------------------------------------------------------------
// pg[b,m] = g_features[b] @ Wg + bg
// ---------------------------------------------------------------------------
__global__ void __launch_bounds__(64) proj_graph(
    const float* __restrict__ g_features,
    const float* __restrict__ Wg, const float* __restrict__ bg,
    float* __restrict__ pg)
{
    const int b = blockIdx.x, m = threadIdx.x;
    float acc = bg[m];
    for (int k = 0; k < DG_; ++k)
        acc += g_features[b * DG_ + k] * Wg[k * MID_ + m];
    pg[b * MID_ + m] = acc;
}

// ---------------------------------------------------------------------------
// Main fused kernel: one block per (b,i) row.
//  Pass A: logits[j] = leaky(p1[j]+p2[i]+pg+be + e[i,j]@We) @ Wa + ba + mask
//          16 threads per j (each owns 4 of 64 mid-cols; We slice in REGS).
//  Pass B: block softmax over j (exp stored back into lg[]).
//  Pass C: out[i,:] = relu( (exp @ values)/denom + skip[i,:] )
// ---------------------------------------------------------------------------
__global__ void __launch_bounds__(256) gat_main(
    const float* __restrict__ e_features, const float* __restrict__ adj,
    const float* __restrict__ We, const float* __restrict__ be,
    const float* __restrict__ Wa, const float* __restrict__ ba,
    const float* __restrict__ values, const float* __restrict__ skipo,
    const float* __restrict__ p1, const float* __restrict__ p2,
    const float* __restrict__ pg, float* __restrict__ out)
{
    const int t  = threadIdx.x;
    const int r  = blockIdx.x;
    const int b  = r >> 10;
    const int i  = r & (N_ - 1);
    const int jg = t >> 4;      // 0..15 : which j within a 16-j chunk
    const int ml = t & 15;      // 0..15 : which 4-col slice of mid
    const int mb = ml * 4;

    __shared__ float  lg[N_];
    __shared__ float4 redv[256];
    __shared__ float  swm[4], sws[4];

    // We slice (16 k x 4 m) held in registers — no LDS in the inner loop.
    float we[64];
    #pragma unroll
    for (int k = 0; k < DE_; ++k) {
        const float4 w = *(const float4*)&We[k * MID_ + mb];
        we[4*k+0] = w.x; we[4*k+1] = w.y; we[4*k+2] = w.z; we[4*k+3] = w.w;
    }
    const float4 wa = *(const float4*)&Wa[mb];
    float4 bbv;
    {
        const float4 a = *(const float4*)&p2[((size_t)(b * N_ + i)) * MID_ + mb];
        const float4 c = *(const float4*)&pg[b * MID_ + mb];
        const float4 d = *(const float4*)&be[mb];
        bbv.x = a.x + c.x + d.x;
        bbv.y = a.y + c.y + d.y;
        bbv.z = a.z + c.z + d.z;
        bbv.w = a.w + c.w + d.w;
    }
    const float  ba0     = ba[0];
    const size_t rowbase = ((size_t)(b * N_ + i)) * N_;

    // ---- Pass A: logits ----
    for (int jc = 0; jc < N_; jc += 16) {
        const int j = jc + jg;
        const float* ep = e_features + (rowbase + j) * DE_;
        float ev[16];
        #pragma unroll
        for (int q = 0; q < 4; ++q) {
            const float4 v = ((const float4*)ep)[q];
            ev[4*q+0] = v.x; ev[4*q+1] = v.y; ev[4*q+2] = v.z; ev[4*q+3] = v.w;
        }
        const float4 p = *(const float4*)&p1[((size_t)(b * N_ + j)) * MID_ + mb];
        float pr0 = bbv.x + p.x, pr1 = bbv.y + p.y;
        float pr2 = bbv.z + p.z, pr3 = bbv.w + p.w;
        #pragma unroll
        for (int k = 0; k < DE_; ++k) {
            const float ek = ev[k];
            pr0 += ek * we[4*k+0];
            pr1 += ek * we[4*k+1];
            pr2 += ek * we[4*k+2];
            pr3 += ek * we[4*k+3];
        }
        const float x0 = pr0 > 0.f ? pr0 : 0.01f * pr0;
        const float x1 = pr1 > 0.f ? pr1 : 0.01f * pr1;
        const float x2 = pr2 > 0.f ? pr2 : 0.01f * pr2;
        const float x3 = pr3 > 0.f ? pr3 : 0.01f * pr3;
        float s = x0 * wa.x + x1 * wa.y + x2 * wa.z + x3 * wa.w;
        s += __shfl_xor(s, 1);
        s += __shfl_xor(s, 2);
        s += __shfl_xor(s, 4);
        s += __shfl_xor(s, 8);
        if (ml == 0) {
            const float a = adj[rowbase + j];
            lg[j] = s + ba0 + (a - 1.0f) * 1e9f;
        }
    }
    __syncthreads();

    // ---- Pass B: softmax over j ----
    float lm = -3.4e38f;
    #pragma unroll
    for (int q = 0; q < 4; ++q) lm = fmaxf(lm, lg[t + 256 * q]);
    #pragma unroll
    for (int o = 32; o > 0; o >>= 1) lm = fmaxf(lm, __shfl_xor(lm, o));
    if ((t & 63) == 0) swm[t >> 6] = lm;
    __syncthreads();
    const float rowmax = fmaxf(fmaxf(swm[0], swm[1]), fmaxf(swm[2], swm[3]));
    float ls = 0.f;
    #pragma unroll
    for (int q = 0; q < 4; ++q) {
        const float e = __expf(lg[t + 256 * q] - rowmax);
        lg[t + 256 * q] = e;      // each thread owns its 4 slots
        ls += e;
    }
    #pragma unroll
    for (int o = 32; o > 0; o >>= 1) ls += __shfl_xor(ls, o);
    if ((t & 63) == 0) sws[t >> 6] = ls;
    __syncthreads();
    const float inv = 1.0f / (sws[0] + sws[1] + sws[2] + sws[3]);

    // ---- Pass C: weighted sum of values + skip + relu ----
    const int c4 = (t & 31) * 4;   // channel group
    const int jp = t >> 5;         // 0..7 : j-partition
    float4 acc = make_float4(0.f, 0.f, 0.f, 0.f);
    for (int j = jp; j < N_; j += 8) {
        const float w = lg[j];
        if (w != 0.f) {
            const float4 v = *(const float4*)&values[((size_t)(b * N_ + j)) * OUT_ + c4];
            acc.x += w * v.x; acc.y += w * v.y;
            acc.z += w * v.z; acc.w += w * v.w;
        }
    }
    redv[t] = acc;
    __syncthreads();
    if (t < 32) {
        float4 a = redv[t];
        #pragma unroll
        for (int q = 1; q < 8; ++q) {
            const float4 x = redv[q * 32 + t];
            a.x += x.x; a.y += x.y; a.z += x.z; a.w += x.w;
        }
        const size_t ob = ((size_t)(b * N_ + i)) * OUT_ + 4 * t;
        const float4 sk = *(const float4*)&skipo[ob];
        float4 o;
        o.x = fmaxf(a.x * inv + sk.x, 0.f);
        o.y = fmaxf(a.y * inv + sk.y, 0.f);
        o.z = fmaxf(a.z * inv + sk.z, 0.f);
        o.w = fmaxf(a.w * inv + sk.w, 0.f);
        *(float4*)&out[ob] = o;
    }
}

extern "C" void kernel_launch(void* const* d_in, const int* in_sizes, int n_in,
                              void* d_out, int out_size, void* d_ws, size_t ws_size,
                              hipStream_t stream) {
    const float* features   = (const float*)d_in[0];
    const float* e_features = (const float*)d_in[1];
    const float* g_features = (const float*)d_in[2];
    const float* adj        = (const float*)d_in[3];
    const float* Wm    = (const float*)d_in[4];
    const float* bm    = (const float*)d_in[5];
    const float* Wskip = (const float*)d_in[6];
    const float* bskip = (const float*)d_in[7];
    const float* W1    = (const float*)d_in[8];
    const float* b1    = (const float*)d_in[9];
    const float* W2    = (const float*)d_in[10];
    const float* b2    = (const float*)d_in[11];
    const float* We    = (const float*)d_in[12];
    const float* be    = (const float*)d_in[13];
    const float* Wg    = (const float*)d_in[14];
    const float* bg    = (const float*)d_in[15];
    const float* Wa    = (const float*)d_in[16];
    const float* ba    = (const float*)d_in[17];
    float* out = (float*)d_out;

    float* ws     = (float*)d_ws;
    float* values = ws;                 // B*N*OUT  = 262144
    float* skipo  = ws + 262144;        // B*N*OUT  = 262144
    float* p1     = ws + 524288;        // B*N*MID  = 131072
    float* p2     = ws + 655360;        // B*N*MID  = 131072
    float* pg     = ws + 786432;        // B*MID    = 128

    proj_rows <<<B_ * N_ / 8, 128, 0, stream>>>(features, Wm, bm, Wskip, bskip,
                                                W1, b1, W2, b2,
                                                values, skipo, p1, p2);
    proj_graph<<<B_, MID_, 0, stream>>>(g_features, Wg, bg, pg);
    gat_main  <<<B_ * N_, 256, 0, stream>>>(e_features, adj, We, be, Wa, ba,
                                            values, skipo, p1, p2, pg, out);
}

// Round 3
// 371.749 us; speedup vs baseline: 1.7169x; 1.7169x over previous
//
#include <hip/hip_runtime.h>
#include <cstdint>

#define B_   2
#define N_   1024
#define DN_  128
#define DE_  16
#define DG_  128
#define MID_ 64
#define OUT_ 128

typedef short bf16x8 __attribute__((ext_vector_type(8)));
typedef float f32x4  __attribute__((ext_vector_type(4)));

__device__ inline short f2bf(float f) {
    union { float f; unsigned u; } v; v.f = f;
    unsigned r = v.u + 0x7FFFu + ((v.u >> 16) & 1u);   // RTNE
    return (short)(unsigned short)(r >> 16);
}

// ---------------------------------------------------------------------------
// pg[b,m] = g_features[b] @ Wg + bg
// ---------------------------------------------------------------------------
__global__ void __launch_bounds__(64) proj_graph(
    const float* __restrict__ g_features,
    const float* __restrict__ Wg, const float* __restrict__ bg,
    float* __restrict__ pg)
{
    const int b = blockIdx.x, m = threadIdx.x;
    float acc = bg[m];
    for (int k = 0; k < DG_; ++k)
        acc += g_features[b * DG_ + k] * Wg[k * MID_ + m];
    pg[b * MID_ + m] = acc;
}

// ---------------------------------------------------------------------------
// Pre-swizzle We into the MFMA B-operand fragment layout (bf16, K padded
// 16->32 with zeros).  We_frag[(c*64 + lane)*8 + j] = We[quad*8+j][c*16+s]
// for quad<2 else 0, where quad=lane>>4, s=lane&15.
// ---------------------------------------------------------------------------
__global__ void __launch_bounds__(256) prep_we(
    const float* __restrict__ We, short* __restrict__ We_frag)
{
    for (int e = threadIdx.x; e < 4 * 64 * 8; e += 256) {
        const int c    = e >> 9;
        const int lane = (e >> 3) & 63;
        const int j    = e & 7;
        const int quad = lane >> 4, s = lane & 15;
        const int k    = quad * 8 + j;
        short v = 0;
        if (quad < 2) v = f2bf(We[k * MID_ + c * 16 + s]);
        We_frag[e] = v;
    }
}

// ---------------------------------------------------------------------------
// Per-node projections, 4 rows per block, one thread per output column of
// the concatenated [values(128) | skip(128) | P1x(64) | p2(64)] output.
// P1x = features@W1 + b1 + be + pg  (row-invariant terms folded in).
// ---------------------------------------------------------------------------
#define PR_ROWS 4
__global__ void __launch_bounds__(384) proj_rows(
    const float* __restrict__ features,
    const float* __restrict__ Wm, const float* __restrict__ bm,
    const float* __restrict__ Wskip, const float* __restrict__ bskip,
    const float* __restrict__ W1, const float* __restrict__ b1,
    const float* __restrict__ W2, const float* __restrict__ b2,
    const float* __restrict__ be, const float* __restrict__ pg,
    float* __restrict__ values, float* __restrict__ skipo,
    float* __restrict__ P1x, float* __restrict__ p2)
{
    const int t  = threadIdx.x;
    const int r0 = blockIdx.x * PR_ROWS;
    const int b  = r0 >> 10;
    __shared__ float feat[PR_ROWS][DN_];
    for (int idx = t; idx < PR_ROWS * DN_; idx += 384)
        feat[idx >> 7][idx & 127] = features[(size_t)r0 * DN_ + idx];
    __syncthreads();

    const float* W; int c, stride; float base; float* outp; int ostride;
    if (t < 128) {
        W = Wm;    c = t;       stride = OUT_; base = bm[c];
        outp = values + (size_t)r0 * OUT_ + c; ostride = OUT_;
    } else if (t < 256) {
        W = Wskip; c = t - 128; stride = OUT_; base = bskip[c];
        outp = skipo + (size_t)r0 * OUT_ + c;  ostride = OUT_;
    } else if (t < 320) {
        W = W1;    c = t - 256; stride = MID_;
        base = b1[c] + be[c] + pg[b * MID_ + c];
        outp = P1x + (size_t)r0 * MID_ + c;    ostride = MID_;
    } else {
        W = W2;    c = t - 320; stride = MID_; base = b2[c];
        outp = p2 + (size_t)r0 * MID_ + c;     ostride = MID_;
    }

    float acc[PR_ROWS] = {};
    for (int k = 0; k < DN_; ++k) {
        const float w = W[k * stride + c];
        #pragma unroll
        for (int q = 0; q < PR_ROWS; ++q) acc[q] += feat[q][k] * w;
    }
    #pragma unroll
    for (int q = 0; q < PR_ROWS; ++q) outp[q * ostride] = acc[q] + base;
}

// ---------------------------------------------------------------------------
// Main fused kernel: one block per (b,i) row, 4 waves.
//  Pass A (MFMA): per 16-j tile, A = e[i,j0:j0+16,0:16] (bf16, K padded to
//  32), B = We frags, C init = P1x[j,:]+p2[i,:].  Epilogue: leaky = fmax(x,
//  0.01x), dot with Wa across 64 mids (4 chunks in-lane + shfl over 16
//  lanes), mask, store logits to LDS.
//  Pass B: block softmax.  Pass C: (exp @ values)/denom + skip, relu.
// ---------------------------------------------------------------------------
__global__ void __launch_bounds__(256) gat_main(
    const float* __restrict__ e_features, const float* __restrict__ adj,
    const short* __restrict__ We_frag, const float* __restrict__ Wa,
    const float* __restrict__ ba,
    const float* __restrict__ values, const float* __restrict__ skipo,
    const float* __restrict__ P1x, const float* __restrict__ p2,
    float* __restrict__ out)
{
    const int t    = threadIdx.x;
    const int r    = blockIdx.x;
    const int b    = r >> 10;
    const int i    = r & (N_ - 1);
    const int wv   = t >> 6;
    const int l    = t & 63;
    const int quad = l >> 4;
    const int s    = l & 15;

    __shared__ float  lg[N_];
    __shared__ float4 redv[256];
    __shared__ float  swm[4], sws[4];

    // Per-block constants
    bf16x8 bfr[4];
    float  wa_r[4], p2i[4];
    #pragma unroll
    for (int c = 0; c < 4; ++c) {
        bfr[c]  = *(const bf16x8*)&We_frag[(c * 64 + l) * 8];
        wa_r[c] = Wa[c * 16 + s];
        p2i[c]  = p2[((size_t)(b * N_ + i)) * MID_ + c * 16 + s];
    }
    const float  ba0     = ba[0];
    const size_t rowbase = ((size_t)(b * N_ + i)) * N_;

    // ---- Pass A ----
    for (int tile = wv; tile < N_ / 16; tile += 4) {
        const int j0 = tile * 16;
        bf16x8 af = {0, 0, 0, 0, 0, 0, 0, 0};
        if (quad < 2) {
            const float* ep = &e_features[(rowbase + j0 + s) * DE_ + quad * 8];
            const float4 u0 = *(const float4*)ep;
            const float4 u1 = *(const float4*)(ep + 4);
            af[0] = f2bf(u0.x); af[1] = f2bf(u0.y);
            af[2] = f2bf(u0.z); af[3] = f2bf(u0.w);
            af[4] = f2bf(u1.x); af[5] = f2bf(u1.y);
            af[6] = f2bf(u1.z); af[7] = f2bf(u1.w);
        }
        // C init = P1x[j] + p2[i]
        const float* pb = &P1x[((size_t)(b * N_ + j0 + quad * 4)) * MID_ + s];
        f32x4 acc[4];
        #pragma unroll
        for (int c = 0; c < 4; ++c) {
            #pragma unroll
            for (int rr = 0; rr < 4; ++rr)
                acc[c][rr] = pb[rr * MID_ + c * 16] + p2i[c];
        }
        #pragma unroll
        for (int c = 0; c < 4; ++c)
            acc[c] = __builtin_amdgcn_mfma_f32_16x16x32_bf16(af, bfr[c], acc[c], 0, 0, 0);

        float tt[4];
        #pragma unroll
        for (int rr = 0; rr < 4; ++rr) {
            float x0 = acc[0][rr], x1 = acc[1][rr], x2 = acc[2][rr], x3 = acc[3][rr];
            x0 = fmaxf(x0, 0.01f * x0);
            x1 = fmaxf(x1, 0.01f * x1);
            x2 = fmaxf(x2, 0.01f * x2);
            x3 = fmaxf(x3, 0.01f * x3);
            tt[rr] = x0 * wa_r[0] + x1 * wa_r[1] + x2 * wa_r[2] + x3 * wa_r[3];
        }
        #pragma unroll
        for (int o = 1; o < 16; o <<= 1) {
            tt[0] += __shfl_xor(tt[0], o);
            tt[1] += __shfl_xor(tt[1], o);
            tt[2] += __shfl_xor(tt[2], o);
            tt[3] += __shfl_xor(tt[3], o);
        }
        if (s < 4) {
            const int j = j0 + quad * 4 + s;
            const float a = adj[rowbase + j];
            lg[j] = tt[s] + ba0 + (a - 1.0f) * 1e9f;
        }
    }
    __syncthreads();

    // ---- Pass B: softmax over j ----
    float lm = -3.4e38f;
    #pragma unroll
    for (int q = 0; q < 4; ++q) lm = fmaxf(lm, lg[t + 256 * q]);
    #pragma unroll
    for (int o = 32; o > 0; o >>= 1) lm = fmaxf(lm, __shfl_xor(lm, o));
    if ((t & 63) == 0) swm[t >> 6] = lm;
    __syncthreads();
    const float rowmax = fmaxf(fmaxf(swm[0], swm[1]), fmaxf(swm[2], swm[3]));
    float ls = 0.f;
    #pragma unroll
    for (int q = 0; q < 4; ++q) {
        const float e = __expf(lg[t + 256 * q] - rowmax);
        lg[t + 256 * q] = e;
        ls += e;
    }
    #pragma unroll
    for (int o = 32; o > 0; o >>= 1) ls += __shfl_xor(ls, o);
    if ((t & 63) == 0) sws[t >> 6] = ls;
    __syncthreads();
    const float inv = 1.0f / (sws[0] + sws[1] + sws[2] + sws[3]);

    // ---- Pass C: weighted sum of values + skip + relu ----
    const int c4 = (t & 31) * 4;
    const int jp = t >> 5;
    float4 acc = make_float4(0.f, 0.f, 0.f, 0.f);
    for (int j = jp; j < N_; j += 8) {
        const float w = lg[j];
        if (w != 0.f) {
            const float4 v = *(const float4*)&values[((size_t)(b * N_ + j)) * OUT_ + c4];
            acc.x += w * v.x; acc.y += w * v.y;
            acc.z += w * v.z; acc.w += w * v.w;
        }
    }
    redv[t] = acc;
    __syncthreads();
    if (t < 32) {
        float4 a = redv[t];
        #pragma unroll
        for (int q = 1; q < 8; ++q) {
            const float4 x = redv[q * 32 + t];
            a.x += x.x; a.y += x.y; a.z += x.z; a.w += x.w;
        }
        const size_t ob = ((size_t)(b * N_ + i)) * OUT_ + 4 * t;
        const float4 sk = *(const float4*)&skipo[ob];
        float4 o;
        o.x = fmaxf(a.x * inv + sk.x, 0.f);
        o.y = fmaxf(a.y * inv + sk.y, 0.f);
        o.z = fmaxf(a.z * inv + sk.z, 0.f);
        o.w = fmaxf(a.w * inv + sk.w, 0.f);
        *(float4*)&out[ob] = o;
    }
}

extern "C" void kernel_launch(void* const* d_in, const int* in_sizes, int n_in,
                              void* d_out, int out_size, void* d_ws, size_t ws_size,
                              hipStream_t stream) {
    const float* features   = (const float*)d_in[0];
    const float* e_features = (const float*)d_in[1];
    const float* g_features = (const float*)d_in[2];
    const float* adj        = (const float*)d_in[3];
    const float* Wm    = (const float*)d_in[4];
    const float* bm    = (const float*)d_in[5];
    const float* Wskip = (const float*)d_in[6];
    const float* bskip = (const float*)d_in[7];
    const float* W1    = (const float*)d_in[8];
    const float* b1    = (const float*)d_in[9];
    const float* W2    = (const float*)d_in[10];
    const float* b2    = (const float*)d_in[11];
    const float* We    = (const float*)d_in[12];
    const float* be    = (const float*)d_in[13];
    const float* Wg    = (const float*)d_in[14];
    const float* bg    = (const float*)d_in[15];
    const float* Wa    = (const float*)d_in[16];
    const float* ba    = (const float*)d_in[17];
    float* out = (float*)d_out;

    float* ws      = (float*)d_ws;
    float* values  = ws;                 // 262144
    float* skipo   = ws + 262144;        // 262144
    float* P1x     = ws + 524288;        // 131072
    float* p2      = ws + 655360;        // 131072
    float* pg      = ws + 786432;        // 128
    short* We_frag = (short*)(ws + 786560); // 2048 shorts = 1024 floats

    proj_graph<<<B_, MID_, 0, stream>>>(g_features, Wg, bg, pg);
    prep_we   <<<1, 256, 0, stream>>>(We, We_frag);
    proj_rows <<<B_ * N_ / PR_ROWS, 384, 0, stream>>>(
        features, Wm, bm, Wskip, bskip, W1, b1, W2, b2, be, pg,
        values, skipo, P1x, p2);
    gat_main  <<<B_ * N_, 256, 0, stream>>>(
        e_features, adj, We_frag, Wa, ba, values, skipo, P1x, p2, out);
}

// Round 4
// 329.284 us; speedup vs baseline: 1.9383x; 1.1290x over previous
//
#include <hip/hip_runtime.h>
#include <hip/hip_bf16.h>
#include <cstdint>

#define B_   2
#define N_   1024
#define DN_  128
#define DE_  16
#define DG_  128
#define MID_ 64
#define OUT_ 128
#define TI_  4
#define PR_ROWS 4

typedef short bf16x8 __attribute__((ext_vector_type(8)));
typedef float f32x4  __attribute__((ext_vector_type(4)));

__device__ inline short f2bf(float f) {
    union { float f; unsigned u; } v; v.f = f;
    unsigned r = v.u + 0x7FFFu + ((v.u >> 16) & 1u);   // RTNE
    return (short)(unsigned short)(r >> 16);
}

__device__ inline unsigned pk2(float lo, float hi) {
    union { __hip_bfloat162 h; unsigned u; } p;
    p.h = __float22bfloat162_rn(make_float2(lo, hi));  // v_cvt_pk_bf16_f32
    return p.u;
}

// ---------------------------------------------------------------------------
// Fused prep kernel.
//  blocks 0..511 : per-node projections, 4 rows/block, one thread per output
//                  column of [values(128)|skip(128)|P1x(64)|p2(64)].
//                  P1x = f@W1 + b1 + be   (pg added later in gat_main)
//  block 512     : We -> MFMA B-fragment layout (bf16, K 16->32 zero-pad)
//  block 513     : pg[b] = g@Wg + bg  (both batches)
// ---------------------------------------------------------------------------
__global__ void __launch_bounds__(384) prep_all(
    const float* __restrict__ features, const float* __restrict__ g_features,
    const float* __restrict__ Wm, const float* __restrict__ bm,
    const float* __restrict__ Wskip, const float* __restrict__ bskip,
    const float* __restrict__ W1, const float* __restrict__ b1,
    const float* __restrict__ W2, const float* __restrict__ b2,
    const float* __restrict__ We, const float* __restrict__ be,
    const float* __restrict__ Wg, const float* __restrict__ bg,
    float* __restrict__ values, float* __restrict__ skipo,
    float* __restrict__ P1x, float* __restrict__ p2,
    float* __restrict__ pg, short* __restrict__ We_frag)
{
    const int t   = threadIdx.x;
    const int blk = blockIdx.x;

    if (blk == 512) {                       // --- We fragment prep ---
        for (int e = t; e < 4 * 64 * 8; e += 384) {
            const int c    = e >> 9;
            const int lane = (e >> 3) & 63;
            const int j    = e & 7;
            const int quad = lane >> 4, s = lane & 15;
            short v = 0;
            if (quad < 2) v = f2bf(We[(quad * 8 + j) * MID_ + c * 16 + s]);
            We_frag[e] = v;
        }
        return;
    }
    if (blk == 513) {                       // --- pg ---
        if (t < MID_) {
            float a0 = bg[t], a1 = bg[t];
            for (int k = 0; k < DG_; ++k) {
                const float w = Wg[k * MID_ + t];
                a0 += g_features[k] * w;
                a1 += g_features[DG_ + k] * w;
            }
            pg[t] = a0; pg[MID_ + t] = a1;
        }
        return;
    }

    // --- per-node projections ---
    const int r0 = blk * PR_ROWS;
    __shared__ float feat[PR_ROWS][DN_];
    for (int idx = t; idx < PR_ROWS * DN_; idx += 384)
        feat[idx >> 7][idx & 127] = features[(size_t)r0 * DN_ + idx];
    __syncthreads();

    const float* W; int c, stride; float base; float* outp; int ostride;
    if (t < 128) {
        W = Wm;    c = t;       stride = OUT_; base = bm[c];
        outp = values + (size_t)r0 * OUT_ + c; ostride = OUT_;
    } else if (t < 256) {
        W = Wskip; c = t - 128; stride = OUT_; base = bskip[c];
        outp = skipo + (size_t)r0 * OUT_ + c;  ostride = OUT_;
    } else if (t < 320) {
        W = W1;    c = t - 256; stride = MID_; base = b1[c] + be[c];
        outp = P1x + (size_t)r0 * MID_ + c;    ostride = MID_;
    } else {
        W = W2;    c = t - 320; stride = MID_; base = b2[c];
        outp = p2 + (size_t)r0 * MID_ + c;     ostride = MID_;
    }

    float acc[PR_ROWS] = {};
    for (int k = 0; k < DN_; ++k) {
        const float w = W[k * stride + c];
        #pragma unroll
        for (int q = 0; q < PR_ROWS; ++q) acc[q] += feat[q][k] * w;
    }
    #pragma unroll
    for (int q = 0; q < PR_ROWS; ++q) outp[q * ostride] = acc[q] + base;
}

// ---------------------------------------------------------------------------
// Main fused kernel: one block per 4 consecutive i-rows (512 blocks x 512
// threads, 8 waves).  Pass A: MFMA logits for 4 i x 1024 j (P1x tile loads
// amortized over the 4 i's).  Pass B: 4 row softmaxes (wave w = row w).
// Pass C: coefs @ values with each values row shared by all 4 i-rows.
// ---------------------------------------------------------------------------
__global__ void __launch_bounds__(512, 4) gat_main(
    const float* __restrict__ e_features, const float* __restrict__ adj,
    const short* __restrict__ We_frag, const float* __restrict__ Wa,
    const float* __restrict__ ba,
    const float* __restrict__ values, const float* __restrict__ skipo,
    const float* __restrict__ P1x, const float* __restrict__ p2,
    const float* __restrict__ pg, float* __restrict__ out)
{
    const int t    = threadIdx.x;
    const int wv   = t >> 6;            // wave 0..7
    const int l    = t & 63;
    const int quad = l >> 4;
    const int s    = l & 15;
    const int r    = blockIdx.x;        // 0..511
    const int b    = r >> 8;
    const int i0   = (r & 255) * TI_;

    __shared__ float lgT[N_][8];        // [j][ii 0..3 | pad] (32B rows, b128-aligned)
    __shared__ float redv[8][16][33];   // [wave][cg][ii*8+k], +1 pad vs banks
    __shared__ float sinv[TI_];

    // ---- block constants ----
    bf16x8 bfr[4];
    float  wa_r[4], p2i[TI_][4];
    #pragma unroll
    for (int c = 0; c < 4; ++c) {
        bfr[c]  = *(const bf16x8*)&We_frag[(c * 64 + l) * 8];
        wa_r[c] = Wa[c * 16 + s];
        const float pgc = pg[b * MID_ + c * 16 + s];
        #pragma unroll
        for (int ii = 0; ii < TI_; ++ii)
            p2i[ii][c] = p2[((size_t)(b * N_ + i0 + ii)) * MID_ + c * 16 + s] + pgc;
    }
    const float ba0 = ba[0];

    // ---- Pass A: logits ----
    for (int tile = wv; tile < N_ / 16; tile += 8) {
        const int j0 = tile * 16;
        float base[4][4];
        {
            const float* pb = &P1x[((size_t)(b * N_ + j0 + quad * 4)) * MID_ + s];
            #pragma unroll
            for (int c = 0; c < 4; ++c)
                #pragma unroll
                for (int rr = 0; rr < 4; ++rr)
                    base[c][rr] = pb[rr * MID_ + c * 16];
        }
        for (int ii = 0; ii < TI_; ++ii) {
            const size_t rb = ((size_t)(b * N_ + i0 + ii)) * (size_t)N_;
            union { bf16x8 v; unsigned u[4]; } a;
            a.u[0] = a.u[1] = a.u[2] = a.u[3] = 0u;
            if (quad < 2) {
                const float* ep = &e_features[(rb + j0 + s) * DE_ + quad * 8];
                const float4 u0 = *(const float4*)ep;
                const float4 u1 = *(const float4*)(ep + 4);
                a.u[0] = pk2(u0.x, u0.y);
                a.u[1] = pk2(u0.z, u0.w);
                a.u[2] = pk2(u1.x, u1.y);
                a.u[3] = pk2(u1.z, u1.w);
            }
            f32x4 acc[4];
            #pragma unroll
            for (int c = 0; c < 4; ++c)
                #pragma unroll
                for (int rr = 0; rr < 4; ++rr)
                    acc[c][rr] = base[c][rr] + p2i[ii][c];
            #pragma unroll
            for (int c = 0; c < 4; ++c)
                acc[c] = __builtin_amdgcn_mfma_f32_16x16x32_bf16(a.v, bfr[c], acc[c], 0, 0, 0);

            float tt[4];
            #pragma unroll
            for (int rr = 0; rr < 4; ++rr) {
                float x0 = acc[0][rr]; x0 = fmaxf(x0, 0.01f * x0);
                float x1 = acc[1][rr]; x1 = fmaxf(x1, 0.01f * x1);
                float x2 = acc[2][rr]; x2 = fmaxf(x2, 0.01f * x2);
                float x3 = acc[3][rr]; x3 = fmaxf(x3, 0.01f * x3);
                tt[rr] = x0 * wa_r[0] + x1 * wa_r[1] + x2 * wa_r[2] + x3 * wa_r[3];
            }
            #pragma unroll
            for (int o = 1; o < 16; o <<= 1) {
                tt[0] += __shfl_xor(tt[0], o);
                tt[1] += __shfl_xor(tt[1], o);
                tt[2] += __shfl_xor(tt[2], o);
                tt[3] += __shfl_xor(tt[3], o);
            }
            if (s < 4) {
                const int j = j0 + quad * 4 + s;
                const float av = adj[rb + j];
                lgT[j][ii] = tt[s] + ba0 + (av - 1.0f) * 1e9f;
            }
        }
    }
    __syncthreads();

    // ---- Pass B: softmax (wave w owns row w) ----
    if (wv < TI_) {
        float v[16];
        float m = -3.4e38f;
        #pragma unroll
        for (int q = 0; q < 16; ++q) {
            v[q] = lgT[l + 64 * q][wv];
            m = fmaxf(m, v[q]);
        }
        #pragma unroll
        for (int o = 1; o < 64; o <<= 1) m = fmaxf(m, __shfl_xor(m, o));
        float sum = 0.f;
        #pragma unroll
        for (int q = 0; q < 16; ++q) {
            const float e = __expf(v[q] - m);
            lgT[l + 64 * q][wv] = e;
            sum += e;
        }
        #pragma unroll
        for (int o = 1; o < 64; o <<= 1) sum += __shfl_xor(sum, o);
        if (l == 0) sinv[wv] = 1.0f / sum;
    }
    __syncthreads();

    // ---- Pass C: (exp @ values) shared across the 4 i-rows ----
    const int cg  = t & 15;             // channel group (8 ch each)
    const int jp  = t >> 4;             // j partition 0..31
    const int ch0 = cg * 8;
    float acc[TI_][8] = {};
    const float* vbase = values + (size_t)b * N_ * OUT_ + ch0;
    for (int j = jp; j < N_; j += 32) {
        const float4 cf = *(const float4*)&lgT[j][0];
        const float* vp = vbase + (size_t)j * OUT_;
        const float4 v0 = *(const float4*)vp;
        const float4 v1 = *(const float4*)(vp + 4);
        const float vv[8] = {v0.x, v0.y, v0.z, v0.w, v1.x, v1.y, v1.z, v1.w};
        const float cw[4] = {cf.x, cf.y, cf.z, cf.w};
        #pragma unroll
        for (int ii = 0; ii < TI_; ++ii)
            #pragma unroll
            for (int k = 0; k < 8; ++k)
                acc[ii][k] += cw[ii] * vv[k];
    }
    // merge the 4 j-partitions within each wave
    #pragma unroll
    for (int ii = 0; ii < TI_; ++ii)
        #pragma unroll
        for (int k = 0; k < 8; ++k) {
            acc[ii][k] += __shfl_xor(acc[ii][k], 16);
            acc[ii][k] += __shfl_xor(acc[ii][k], 32);
        }
    if (l < 16) {
        #pragma unroll
        for (int ii = 0; ii < TI_; ++ii)
            #pragma unroll
            for (int k = 0; k < 8; ++k)
                redv[wv][l][ii * 8 + k] = acc[ii][k];
    }
    __syncthreads();
    // final cross-wave reduce: one thread per output element
    {
        const int ii = t >> 7;          // 0..3
        const int ch = t & 127;
        const int g  = ch >> 3, k = ch & 7;
        float sum = 0.f;
        #pragma unroll
        for (int w = 0; w < 8; ++w) sum += redv[w][g][ii * 8 + k];
        const size_t ob = ((size_t)(b * N_ + i0 + ii)) * OUT_ + ch;
        out[ob] = fmaxf(sum * sinv[ii] + skipo[ob], 0.f);
    }
}

extern "C" void kernel_launch(void* const* d_in, const int* in_sizes, int n_in,
                              void* d_out, int out_size, void* d_ws, size_t ws_size,
                              hipStream_t stream) {
    const float* features   = (const float*)d_in[0];
    const float* e_features = (const float*)d_in[1];
    const float* g_features = (const float*)d_in[2];
    const float* adj        = (const float*)d_in[3];
    const float* Wm    = (const float*)d_in[4];
    const float* bm    = (const float*)d_in[5];
    const float* Wskip = (const float*)d_in[6];
    const float* bskip = (const float*)d_in[7];
    const float* W1    = (const float*)d_in[8];
    const float* b1    = (const float*)d_in[9];
    const float* W2    = (const float*)d_in[10];
    const float* b2    = (const float*)d_in[11];
    const float* We    = (const float*)d_in[12];
    const float* be    = (const float*)d_in[13];
    const float* Wg    = (const float*)d_in[14];
    const float* bg    = (const float*)d_in[15];
    const float* Wa    = (const float*)d_in[16];
    const float* ba    = (const float*)d_in[17];
    float* out = (float*)d_out;

    float* ws      = (float*)d_ws;
    float* values  = ws;                    // 262144
    float* skipo   = ws + 262144;           // 262144
    float* P1x     = ws + 524288;           // 131072
    float* p2      = ws + 655360;           // 131072
    float* pg      = ws + 786432;           // 128
    short* We_frag = (short*)(ws + 786560); // 2048 shorts

    prep_all<<<B_ * N_ / PR_ROWS + 2, 384, 0, stream>>>(
        features, g_features, Wm, bm, Wskip, bskip, W1, b1, W2, b2,
        We, be, Wg, bg, values, skipo, P1x, p2, pg, We_frag);
    gat_main<<<B_ * N_ / TI_, 512, 0, stream>>>(
        e_features, adj, We_frag, Wa, ba, values, skipo, P1x, p2, pg, out);
}

// Round 5
// 297.862 us; speedup vs baseline: 2.1428x; 1.1055x over previous
//
#include <hip/hip_runtime.h>
#include <hip/hip_bf16.h>
#include <cstdint>

#define B_   2
#define N_   1024
#define DN_  128
#define DE_  16
#define DG_  128
#define MID_ 64
#define OUT_ 128
#define TI_  4
#define PR_ROWS 4

typedef short bf16x8 __attribute__((ext_vector_type(8)));
typedef float f32x4  __attribute__((ext_vector_type(4)));

__device__ inline short f2bf(float f) {
    union { float f; unsigned u; } v; v.f = f;
    unsigned r = v.u + 0x7FFFu + ((v.u >> 16) & 1u);   // RTNE
    return (short)(unsigned short)(r >> 16);
}

__device__ inline unsigned pk2(float lo, float hi) {
    union { __hip_bfloat162 h; unsigned u; } p;
    p.h = __float22bfloat162_rn(make_float2(lo, hi));  // v_cvt_pk_bf16_f32
    return p.u;
}

// ---------------------------------------------------------------------------
// Fused prep kernel (same structure as R4 — ~25us, not the bottleneck).
//  blocks 0..511 : per-node projections, 4 rows/block.
//  block 512     : We -> MFMA B-fragment layout (bf16, K 16->32 zero-pad)
//  block 513     : pg[b] = g@Wg + bg
// ---------------------------------------------------------------------------
__global__ void __launch_bounds__(384) prep_all(
    const float* __restrict__ features, const float* __restrict__ g_features,
    const float* __restrict__ Wm, const float* __restrict__ bm,
    const float* __restrict__ Wskip, const float* __restrict__ bskip,
    const float* __restrict__ W1, const float* __restrict__ b1,
    const float* __restrict__ W2, const float* __restrict__ b2,
    const float* __restrict__ We, const float* __restrict__ be,
    const float* __restrict__ Wg, const float* __restrict__ bg,
    float* __restrict__ values, float* __restrict__ skipo,
    float* __restrict__ P1x, float* __restrict__ p2,
    float* __restrict__ pg, short* __restrict__ We_frag)
{
    const int t   = threadIdx.x;
    const int blk = blockIdx.x;

    if (blk == 512) {                       // --- We fragment prep ---
        for (int e = t; e < 4 * 64 * 8; e += 384) {
            const int c    = e >> 9;
            const int lane = (e >> 3) & 63;
            const int j    = e & 7;
            const int quad = lane >> 4, s = lane & 15;
            short v = 0;
            if (quad < 2) v = f2bf(We[(quad * 8 + j) * MID_ + c * 16 + s]);
            We_frag[e] = v;
        }
        return;
    }
    if (blk == 513) {                       // --- pg ---
        if (t < MID_) {
            float a0 = bg[t], a1 = bg[t];
            for (int k = 0; k < DG_; ++k) {
                const float w = Wg[k * MID_ + t];
                a0 += g_features[k] * w;
                a1 += g_features[DG_ + k] * w;
            }
            pg[t] = a0; pg[MID_ + t] = a1;
        }
        return;
    }

    // --- per-node projections ---
    const int r0 = blk * PR_ROWS;
    __shared__ float feat[PR_ROWS][DN_];
    for (int idx = t; idx < PR_ROWS * DN_; idx += 384)
        feat[idx >> 7][idx & 127] = features[(size_t)r0 * DN_ + idx];
    __syncthreads();

    const float* W; int c, stride; float base; float* outp; int ostride;
    if (t < 128) {
        W = Wm;    c = t;       stride = OUT_; base = bm[c];
        outp = values + (size_t)r0 * OUT_ + c; ostride = OUT_;
    } else if (t < 256) {
        W = Wskip; c = t - 128; stride = OUT_; base = bskip[c];
        outp = skipo + (size_t)r0 * OUT_ + c;  ostride = OUT_;
    } else if (t < 320) {
        W = W1;    c = t - 256; stride = MID_; base = b1[c] + be[c];
        outp = P1x + (size_t)r0 * MID_ + c;    ostride = MID_;
    } else {
        W = W2;    c = t - 320; stride = MID_; base = b2[c];
        outp = p2 + (size_t)r0 * MID_ + c;     ostride = MID_;
    }

    float acc[PR_ROWS] = {};
    for (int k = 0; k < DN_; ++k) {
        const float w = W[k * stride + c];
        #pragma unroll
        for (int q = 0; q < PR_ROWS; ++q) acc[q] += feat[q][k] * w;
    }
    #pragma unroll
    for (int q = 0; q < PR_ROWS; ++q) outp[q * ostride] = acc[q] + base;
}

// ---------------------------------------------------------------------------
// Main fused kernel: 512 blocks x 256 threads (4 waves), TI=4 i-rows/block.
// XCD swizzle: b = (blockIdx&4)>>2 so each XCD serves one batch (values L2).
// Pass A: software-pipelined MFMA logits (e prefetch one tile ahead, C-init
//         folded post-MFMA).  lg stored in 4 per-ii LDS planes.
// Pass B: wave ii does masked softmax with coalesced adj row reads.
// Pass C: coefs @ values, values row shared by all 4 i-rows.
// ---------------------------------------------------------------------------
__global__ void __launch_bounds__(256) gat_main(
    const float* __restrict__ e_features, const float* __restrict__ adj,
    const short* __restrict__ We_frag, const float* __restrict__ Wa,
    const float* __restrict__ values, const float* __restrict__ skipo,
    const float* __restrict__ P1x, const float* __restrict__ p2,
    const float* __restrict__ pg, float* __restrict__ out)
{
    const int t    = threadIdx.x;
    const int wv   = t >> 6;
    const int l    = t & 63;
    const int quad = l >> 4;
    const int s    = l & 15;
    const int r    = blockIdx.x;
    const int b    = (r >> 2) & 1;                    // XCD r%8 -> one batch
    const int i0   = (((r >> 3) << 2) | (r & 3)) * TI_;

    __shared__ float lgP[TI_][N_];
    __shared__ float redv[TI_][16][36];
    __shared__ float sinv[TI_];

    // ---- block constants ----
    bf16x8 bfr[4];
    float  wa_r[4], p2i[TI_][4];
    #pragma unroll
    for (int c = 0; c < 4; ++c) {
        bfr[c]  = *(const bf16x8*)&We_frag[(c * 64 + l) * 8];
        wa_r[c] = Wa[c * 16 + s];
        const float pgc = pg[b * MID_ + c * 16 + s];
        #pragma unroll
        for (int ii = 0; ii < TI_; ++ii)
            p2i[ii][c] = p2[((size_t)(b * N_ + i0 + ii)) * MID_ + c * 16 + s] + pgc;
    }
    const size_t erow0 = (size_t)(b * N_ + i0) * N_;  // in e rows

    // ---- Pass A: software-pipelined logits ----
    float4 eA[TI_][2];
    if (quad < 2) {
        #pragma unroll
        for (int ii = 0; ii < TI_; ++ii) {
            const float* ep = &e_features[(erow0 + (size_t)ii * N_ + wv * 16 + s) * DE_ + quad * 8];
            eA[ii][0] = *(const float4*)ep;
            eA[ii][1] = *(const float4*)(ep + 4);
        }
    }
    for (int it = 0; it < 16; ++it) {
        const int tile = wv + it * 4;
        const int j0   = tile * 16;

        // pack current tile's e into bf16 A-fragments
        unsigned af[TI_][4];
        #pragma unroll
        for (int ii = 0; ii < TI_; ++ii) {
            if (quad < 2) {
                af[ii][0] = pk2(eA[ii][0].x, eA[ii][0].y);
                af[ii][1] = pk2(eA[ii][0].z, eA[ii][0].w);
                af[ii][2] = pk2(eA[ii][1].x, eA[ii][1].y);
                af[ii][3] = pk2(eA[ii][1].z, eA[ii][1].w);
            } else {
                af[ii][0] = af[ii][1] = af[ii][2] = af[ii][3] = 0u;
            }
        }
        // prefetch next tile (fire-and-forget; consumed next iteration)
        if (it < 15) {
            const int jn = (tile + 4) * 16;
            if (quad < 2) {
                #pragma unroll
                for (int ii = 0; ii < TI_; ++ii) {
                    const float* ep = &e_features[(erow0 + (size_t)ii * N_ + jn + s) * DE_ + quad * 8];
                    eA[ii][0] = *(const float4*)ep;
                    eA[ii][1] = *(const float4*)(ep + 4);
                }
            }
        }
        // P1x bias tile (off MFMA critical path — consumed in epilogue)
        float base[4][4];
        {
            const float* pb = &P1x[((size_t)(b * N_) + j0 + quad * 4) * MID_ + s];
            #pragma unroll
            for (int c = 0; c < 4; ++c)
                #pragma unroll
                for (int rr = 0; rr < 4; ++rr)
                    base[c][rr] = pb[rr * MID_ + c * 16];
        }
        #pragma unroll
        for (int ii = 0; ii < TI_; ++ii) {
            union { unsigned u[4]; bf16x8 v; } a;
            a.u[0] = af[ii][0]; a.u[1] = af[ii][1];
            a.u[2] = af[ii][2]; a.u[3] = af[ii][3];
            f32x4 acc[4];
            #pragma unroll
            for (int c = 0; c < 4; ++c) {
                acc[c] = (f32x4){0.f, 0.f, 0.f, 0.f};
                acc[c] = __builtin_amdgcn_mfma_f32_16x16x32_bf16(a.v, bfr[c], acc[c], 0, 0, 0);
            }
            float tt[4];
            #pragma unroll
            for (int rr = 0; rr < 4; ++rr) {
                float x0 = acc[0][rr] + base[0][rr] + p2i[ii][0];
                float x1 = acc[1][rr] + base[1][rr] + p2i[ii][1];
                float x2 = acc[2][rr] + base[2][rr] + p2i[ii][2];
                float x3 = acc[3][rr] + base[3][rr] + p2i[ii][3];
                x0 = fmaxf(x0, 0.01f * x0);
                x1 = fmaxf(x1, 0.01f * x1);
                x2 = fmaxf(x2, 0.01f * x2);
                x3 = fmaxf(x3, 0.01f * x3);
                tt[rr] = x0 * wa_r[0] + x1 * wa_r[1] + x2 * wa_r[2] + x3 * wa_r[3];
            }
            #pragma unroll
            for (int o = 1; o < 16; o <<= 1) {
                tt[0] += __shfl_xor(tt[0], o);
                tt[1] += __shfl_xor(tt[1], o);
                tt[2] += __shfl_xor(tt[2], o);
                tt[3] += __shfl_xor(tt[3], o);
            }
            if (s < 4) lgP[ii][j0 + quad * 4 + s] = tt[s];
        }
    }
    __syncthreads();

    // ---- Pass B: masked softmax, wave wv owns plane wv ----
    {
        const size_t arb = (size_t)(b * N_ + i0 + wv) * N_;
        float4 lv[4], av[4];
        #pragma unroll
        for (int q = 0; q < 4; ++q) {
            lv[q] = *(const float4*)&lgP[wv][l * 4 + 256 * q];
            av[q] = *(const float4*)&adj[arb + l * 4 + 256 * q];
        }
        const float NEG = -3.4e38f;
        float m = NEG;
        #pragma unroll
        for (int q = 0; q < 4; ++q) {
            m = fmaxf(m, av[q].x > 0.f ? lv[q].x : NEG);
            m = fmaxf(m, av[q].y > 0.f ? lv[q].y : NEG);
            m = fmaxf(m, av[q].z > 0.f ? lv[q].z : NEG);
            m = fmaxf(m, av[q].w > 0.f ? lv[q].w : NEG);
        }
        #pragma unroll
        for (int o = 1; o < 64; o <<= 1) m = fmaxf(m, __shfl_xor(m, o));
        float sum = 0.f;
        #pragma unroll
        for (int q = 0; q < 4; ++q) {
            float4 e4;
            e4.x = av[q].x > 0.f ? __expf(lv[q].x - m) : 0.f;
            e4.y = av[q].y > 0.f ? __expf(lv[q].y - m) : 0.f;
            e4.z = av[q].z > 0.f ? __expf(lv[q].z - m) : 0.f;
            e4.w = av[q].w > 0.f ? __expf(lv[q].w - m) : 0.f;
            *(float4*)&lgP[wv][l * 4 + 256 * q] = e4;
            sum += (e4.x + e4.y) + (e4.z + e4.w);
        }
        #pragma unroll
        for (int o = 1; o < 64; o <<= 1) sum += __shfl_xor(sum, o);
        if (l == 0) sinv[wv] = 1.0f / sum;
    }
    __syncthreads();

    // ---- Pass C: (exp @ values) shared across the 4 i-rows ----
    const int cg = l & 15, jp = l >> 4, ch0 = cg * 8;
    float acc[TI_][8] = {};
    const float* vb = values + (size_t)b * N_ * OUT_ + ch0;
    for (int k = 0; k < 64; ++k) {
        const int j = wv * 4 + jp + k * 16;
        float cw[TI_];
        #pragma unroll
        for (int ii = 0; ii < TI_; ++ii) cw[ii] = lgP[ii][j];
        const float* vp = vb + (size_t)j * OUT_;
        const float4 v0 = *(const float4*)vp;
        const float4 v1 = *(const float4*)(vp + 4);
        const float vv[8] = {v0.x, v0.y, v0.z, v0.w, v1.x, v1.y, v1.z, v1.w};
        #pragma unroll
        for (int ii = 0; ii < TI_; ++ii)
            #pragma unroll
            for (int kk = 0; kk < 8; ++kk)
                acc[ii][kk] += cw[ii] * vv[kk];
    }
    #pragma unroll
    for (int ii = 0; ii < TI_; ++ii)
        #pragma unroll
        for (int kk = 0; kk < 8; ++kk) {
            acc[ii][kk] += __shfl_xor(acc[ii][kk], 16);
            acc[ii][kk] += __shfl_xor(acc[ii][kk], 32);
        }
    if (l < 16) {
        #pragma unroll
        for (int ii = 0; ii < TI_; ++ii)
            #pragma unroll
            for (int q = 0; q < 2; ++q) {
                float4 w4 = make_float4(acc[ii][q * 4], acc[ii][q * 4 + 1],
                                        acc[ii][q * 4 + 2], acc[ii][q * 4 + 3]);
                *(float4*)&redv[wv][l][ii * 8 + q * 4] = w4;
            }
    }
    __syncthreads();
    {
        const int ch = t & 127, g = ch >> 3, kk = ch & 7;
        const int iib = t >> 7;
        #pragma unroll
        for (int p = 0; p < 2; ++p) {
            const int ii = iib + p * 2;
            const float sum = redv[0][g][ii * 8 + kk] + redv[1][g][ii * 8 + kk]
                            + redv[2][g][ii * 8 + kk] + redv[3][g][ii * 8 + kk];
            const size_t ob = ((size_t)(b * N_ + i0 + ii)) * OUT_ + ch;
            out[ob] = fmaxf(sum * sinv[ii] + skipo[ob], 0.f);
        }
    }
}

extern "C" void kernel_launch(void* const* d_in, const int* in_sizes, int n_in,
                              void* d_out, int out_size, void* d_ws, size_t ws_size,
                              hipStream_t stream) {
    const float* features   = (const float*)d_in[0];
    const float* e_features = (const float*)d_in[1];
    const float* g_features = (const float*)d_in[2];
    const float* adj        = (const float*)d_in[3];
    const float* Wm    = (const float*)d_in[4];
    const float* bm    = (const float*)d_in[5];
    const float* Wskip = (const float*)d_in[6];
    const float* bskip = (const float*)d_in[7];
    const float* W1    = (const float*)d_in[8];
    const float* b1    = (const float*)d_in[9];
    const float* W2    = (const float*)d_in[10];
    const float* b2    = (const float*)d_in[11];
    const float* We    = (const float*)d_in[12];
    const float* be    = (const float*)d_in[13];
    const float* Wg    = (const float*)d_in[14];
    const float* bg    = (const float*)d_in[15];
    const float* Wa    = (const float*)d_in[16];
    float* out = (float*)d_out;

    float* ws      = (float*)d_ws;
    float* values  = ws;                    // 262144
    float* skipo   = ws + 262144;           // 262144
    float* P1x     = ws + 524288;           // 131072
    float* p2      = ws + 655360;           // 131072
    float* pg      = ws + 786432;           // 128
    short* We_frag = (short*)(ws + 786560); // 2048 shorts

    prep_all<<<B_ * N_ / PR_ROWS + 2, 384, 0, stream>>>(
        features, g_features, Wm, bm, Wskip, bskip, W1, b1, W2, b2,
        We, be, Wg, bg, values, skipo, P1x, p2, pg, We_frag);
    gat_main<<<B_ * N_ / TI_, 256, 0, stream>>>(
        e_features, adj, We_frag, Wa, values, skipo, P1x, p2, pg, out);
}